// Round 1
// baseline (386.467 us; speedup 1.0000x reference)
//
#include <hip/hip_runtime.h>
#include <hip/hip_bf16.h>

// Problem: out[s,:] = sum_{i in segment s} (input[i,:] @ W^T + b)
// N = 500000, S = 10000, D_IN = D_OUT = 128.
// Algebraic transform (linear ops commute):
//   out[s] = (sum_{i in seg s} X[i]) @ W^T + count_s * b
// Phase 1: segment row-sum of X (N x 128 -> S x 128): HBM-bound, 256 MB read.
//   Wave-per-segment: 64 lanes = 2 rows x 32 float4 cols, unroll x4
//   (4 loads in flight/lane, wave covers 8 contiguous rows = 4 KB/iter).
//   No LDS, no barriers; cross-parity reduce = 4x shfl_xor(32).
// Phase 2: small GEMM (10000 x 128 x 128) + count*b epilogue: ~5 us.

#define D 128          // D_IN == D_OUT
#define D4 32          // D/4

__device__ __forceinline__ void f4add(float4& a, const float4& v) {
  a.x += v.x; a.y += v.y; a.z += v.z; a.w += v.w;
}

// ---------------- Phase 1: per-segment row sum (wave-per-segment) ----------
__global__ __launch_bounds__(256) void seg_sum_kernel(
    const float* __restrict__ in, const int* __restrict__ graph,
    float* __restrict__ Xs, int N, int S) {
  int s = blockIdx.x * 4 + (threadIdx.x >> 6);
  if (s >= S) return;
  int lane = threadIdx.x & 63;
  int rp   = lane >> 5;   // row parity (0/1)
  int c4   = lane & 31;   // float4 column

  int rs  = graph[2 * s];
  int re  = graph[2 * s + 1];
  int nxt = (s + 1 < S) ? (graph[2 * s + 2] - 1) : (N - 1);
  re = min(re, min(nxt, N - 1));
  rs = max(rs, 0);
  int cnt = max(0, re - rs + 1);

  const float4* p = (const float4*)in + (size_t)rs * D4 + c4;
  float4 a0 = make_float4(0.f, 0.f, 0.f, 0.f);
  float4 a1 = make_float4(0.f, 0.f, 0.f, 0.f);
  float4 a2 = make_float4(0.f, 0.f, 0.f, 0.f);
  float4 a3 = make_float4(0.f, 0.f, 0.f, 0.f);

  int r = rp;
  // rows r, r+2, r+4, r+6 for this parity: 4 independent loads in flight.
  for (; r + 6 < cnt; r += 8) {
    float4 v0 = p[(size_t)(r    ) * D4];
    float4 v1 = p[(size_t)(r + 2) * D4];
    float4 v2 = p[(size_t)(r + 4) * D4];
    float4 v3 = p[(size_t)(r + 6) * D4];
    f4add(a0, v0); f4add(a1, v1); f4add(a2, v2); f4add(a3, v3);
  }
  for (; r < cnt; r += 2) {
    f4add(a0, p[(size_t)r * D4]);
  }
  f4add(a0, a1); f4add(a2, a3); f4add(a0, a2);

  // reduce across the two row-parities: lane <-> lane^32
  a0.x += __shfl_xor(a0.x, 32);
  a0.y += __shfl_xor(a0.y, 32);
  a0.z += __shfl_xor(a0.z, 32);
  a0.w += __shfl_xor(a0.w, 32);

  if (rp == 0) {
    ((float4*)Xs)[(size_t)s * D4 + c4] = a0;
  }
}

// ---------------- Phase 2: out = Xs @ W^T + cnt*b ----------------
// Tile: 16 segments x 64 output cols per 256-thread block.
// Wt LDS tile stored transposed [d][o'] with stride 65 (conflict-free
// stride-1 reads across the wave). Xs tile broadcast-read as float4.
#define SEG_PB 16
#define OUT_PB 64
#define WT_STRIDE 65

__global__ __launch_bounds__(256) void seg_gemm_kernel(
    const float* __restrict__ Xs, const float* __restrict__ W,
    const float* __restrict__ b, const int* __restrict__ graph,
    float* __restrict__ out, int N, int S) {
  __shared__ float Wt[D * WT_STRIDE];             // 33.3 KB
  __shared__ __align__(16) float XsL[SEG_PB * D]; // 8 KB
  __shared__ float cntL[SEG_PB];

  int tid   = threadIdx.x;
  int s0    = blockIdx.x * SEG_PB;
  int oBase = blockIdx.y * OUT_PB;

  // stage W^T tile: rows [oBase, oBase+64), coalesced float4 global reads,
  // scalar LDS writes (stride-65, once per block)
  #pragma unroll
  for (int rnd = 0; rnd < 8; ++rnd) {
    int linear = rnd * 256 + tid;        // 0..2047
    int op     = linear >> 5;            // 0..63 local out row
    int d4     = (linear & 31) << 2;     // 0,4,...,124
    float4 w = *(const float4*)(W + (oBase + op) * D + d4);
    Wt[(d4 + 0) * WT_STRIDE + op] = w.x;
    Wt[(d4 + 1) * WT_STRIDE + op] = w.y;
    Wt[(d4 + 2) * WT_STRIDE + op] = w.z;
    Wt[(d4 + 3) * WT_STRIDE + op] = w.w;
  }
  // stage Xs tile: 2048 floats = 512 float4, 2 rounds
  {
    const float4* src = (const float4*)(Xs + s0 * D);
    float4* dst = (float4*)XsL;
    dst[tid]       = src[tid];
    dst[tid + 256] = src[tid + 256];
  }
  // segment counts (replicates reference valid-mask semantics)
  if (tid < SEG_PB) {
    int s   = s0 + tid;
    int rs  = graph[2 * s];
    int re  = graph[2 * s + 1];
    int nxt = (s + 1 < S) ? (graph[2 * s + 2] - 1) : (N - 1);
    re = min(re, min(nxt, N - 1));
    rs = max(rs, 0);
    cntL[tid] = (float)max(0, re - rs + 1);
  }
  __syncthreads();

  int op = tid & 63;   // local out col; whole wave shares g
  int g  = tid >> 6;   // 0..3 segment phase
  float acc[4] = {0.f, 0.f, 0.f, 0.f};

  const float4* xs4 = (const float4*)XsL;
  #pragma unroll 8
  for (int d4 = 0; d4 < D4; ++d4) {
    float w0 = Wt[(4 * d4 + 0) * WT_STRIDE + op];
    float w1 = Wt[(4 * d4 + 1) * WT_STRIDE + op];
    float w2 = Wt[(4 * d4 + 2) * WT_STRIDE + op];
    float w3 = Wt[(4 * d4 + 3) * WT_STRIDE + op];
    #pragma unroll
    for (int j = 0; j < 4; ++j) {
      float4 x = xs4[(4 * j + g) * D4 + d4];  // LDS broadcast
      acc[j] += x.x * w0 + x.y * w1 + x.z * w2 + x.w * w3;
    }
  }

  float bo = b[oBase + op];
  #pragma unroll
  for (int j = 0; j < 4; ++j) {
    int sl = 4 * j + g;
    out[(s0 + sl) * D + oBase + op] = acc[j] + cntL[sl] * bo;
  }
}

extern "C" void kernel_launch(void* const* d_in, const int* in_sizes, int n_in,
                              void* d_out, int out_size, void* d_ws, size_t ws_size,
                              hipStream_t stream) {
  const float* in    = (const float*)d_in[0];
  const int*   graph = (const int*)d_in[1];
  const float* W     = (const float*)d_in[2];
  const float* b     = (const float*)d_in[3];
  float* out = (float*)d_out;

  const int N = in_sizes[0] / D;     // 500000
  const int S = in_sizes[1] / 2;     // 10000

  float* Xs = (float*)d_ws;          // S*128 floats = 5.12 MB scratch

  seg_sum_kernel<<<(S + 3) / 4, 256, 0, stream>>>(in, graph, Xs, N, S);

  dim3 grid2(S / SEG_PB, D / OUT_PB);  // 625 x 2
  seg_gemm_kernel<<<grid2, 256, 0, stream>>>(Xs, W, b, graph, out, N, S);
}

// Round 2
// 375.706 us; speedup vs baseline: 1.0286x; 1.0286x over previous
//
#include <hip/hip_runtime.h>
#include <hip/hip_bf16.h>

// Problem: out[s,:] = sum_{i in segment s} (input[i,:] @ W^T + b)
// N = 500000, S = 10000, D_IN = D_OUT = 128.
// Algebraic transform (linear ops commute):
//   out[s] = (sum_{i in seg s} X[i]) @ W^T + count_s * b
//
// Phase 1 (this round): CHUNK-based segment row-sum. Work decomposition is
// decoupled from segment boundaries: each block owns a fixed 128-row chunk
// (exactly 64 KB of coalesced reads -> perfect load balance; the previous
// per-segment decompositions lost ~15-20 us to the longest-segment tail).
// Each block binary-searches the segment containing its first row, then
// walks the few segments intersecting the chunk. Fully-contained segments
// are plain-stored; boundary segments accumulate via device-scope atomicAdd
// into a pre-zeroed Xs (L2-resident, ~1M scalar atomics total).
// Phase 2: small GEMM (10000 x 128 x 128) + count*b epilogue: ~5 us.

#define D 128          // D_IN == D_OUT
#define D4 32          // D/4
#define CHUNK 128      // rows per block in phase 1

__device__ __forceinline__ void f4add(float4& a, const float4& v) {
  a.x += v.x; a.y += v.y; a.z += v.z; a.w += v.w;
}

// ---------------- Phase 0: zero the Xs scratch (5 MB) ----------------
__global__ __launch_bounds__(256) void zero_kernel(float4* __restrict__ Xs) {
  Xs[blockIdx.x * 256 + threadIdx.x] = make_float4(0.f, 0.f, 0.f, 0.f);
}

// ---------------- Phase 1: chunked segment row sum ----------------
// 256 threads: rg = tid>>5 (8 row groups), c4 = tid&31 (float4 column).
__global__ __launch_bounds__(256) void seg_sum_kernel(
    const float* __restrict__ in, const int* __restrict__ graph,
    float* __restrict__ Xs, int N, int S) {
  __shared__ float4 red[256];

  int tid = threadIdx.x;
  int rg  = tid >> 5;   // 0..7
  int c4  = tid & 31;   // 0..31

  int c0 = blockIdx.x * CHUNK;
  int c1 = min(c0 + CHUNK, N);   // exclusive

  // binary search: largest s with starts[s] <= c0 (uniform across block)
  int lo = 0, hi = S - 1;
  while (lo < hi) {
    int mid = (lo + hi + 1) >> 1;
    if (graph[2 * mid] <= c0) lo = mid; else hi = mid - 1;
  }

  for (int s = lo; s < S; ++s) {
    int rs = graph[2 * s];
    if (rs > c1 - 1) break;                 // segment starts past our chunk
    int re  = graph[2 * s + 1];
    int nxt = (s + 1 < S) ? (graph[2 * s + 2] - 1) : (N - 1);
    re = min(re, min(nxt, N - 1));          // reference valid-mask semantics
    rs = max(rs, 0);

    int rlo = max(rs, c0);
    int rhi = min(re, c1 - 1);
    if (rlo > rhi) continue;                // empty/gap intersection
    int cnt = rhi - rlo + 1;                // 1..128

    const float4* p = (const float4*)in + (size_t)rlo * D4 + c4;
    float4 a0 = make_float4(0.f, 0.f, 0.f, 0.f);
    float4 a1 = make_float4(0.f, 0.f, 0.f, 0.f);
    float4 a2 = make_float4(0.f, 0.f, 0.f, 0.f);
    float4 a3 = make_float4(0.f, 0.f, 0.f, 0.f);

    int r = rg;
    for (; r + 24 < cnt; r += 32) {         // 4 loads in flight per lane
      float4 v0 = p[(r     ) * D4];
      float4 v1 = p[(r +  8) * D4];
      float4 v2 = p[(r + 16) * D4];
      float4 v3 = p[(r + 24) * D4];
      f4add(a0, v0); f4add(a1, v1); f4add(a2, v2); f4add(a3, v3);
    }
    for (; r < cnt; r += 8) {
      f4add(a0, p[r * D4]);
    }
    f4add(a0, a1); f4add(a2, a3); f4add(a0, a2);

    // reduce the 8 row-groups (tree in LDS)
    red[tid] = a0;
    __syncthreads();
    if (tid < 128) { f4add(red[tid], red[tid + 128]); }
    __syncthreads();
    if (tid < 64)  { f4add(red[tid], red[tid + 64]); }
    __syncthreads();
    if (tid < 32) {
      float4 r4 = red[tid];
      f4add(r4, red[tid + 32]);
      if (rs >= c0 && re <= c1 - 1) {
        // segment fully contained in this chunk: unique writer
        ((float4*)Xs)[(size_t)s * D4 + tid] = r4;
      } else {
        // boundary segment: multiple chunks contribute
        float* dst = Xs + (size_t)s * D + tid * 4;
        atomicAdd(dst + 0, r4.x);
        atomicAdd(dst + 1, r4.y);
        atomicAdd(dst + 2, r4.z);
        atomicAdd(dst + 3, r4.w);
      }
    }
    __syncthreads();   // red[] reused next segment
  }
}

// ---------------- Phase 2: out = Xs @ W^T + cnt*b ----------------
// Tile: 16 segments x 64 output cols per 256-thread block.
// Wt LDS tile stored transposed [d][o'] with stride 65 (conflict-free
// stride-1 reads across the wave). Xs tile broadcast-read as float4.
#define SEG_PB 16
#define OUT_PB 64
#define WT_STRIDE 65

__global__ __launch_bounds__(256) void seg_gemm_kernel(
    const float* __restrict__ Xs, const float* __restrict__ W,
    const float* __restrict__ b, const int* __restrict__ graph,
    float* __restrict__ out, int N, int S) {
  __shared__ float Wt[D * WT_STRIDE];             // 33.3 KB
  __shared__ __align__(16) float XsL[SEG_PB * D]; // 8 KB
  __shared__ float cntL[SEG_PB];

  int tid   = threadIdx.x;
  int s0    = blockIdx.x * SEG_PB;
  int oBase = blockIdx.y * OUT_PB;

  // stage W^T tile: rows [oBase, oBase+64), coalesced float4 global reads,
  // scalar LDS writes (stride-65, once per block)
  #pragma unroll
  for (int rnd = 0; rnd < 8; ++rnd) {
    int linear = rnd * 256 + tid;        // 0..2047
    int op     = linear >> 5;            // 0..63 local out row
    int d4     = (linear & 31) << 2;     // 0,4,...,124
    float4 w = *(const float4*)(W + (oBase + op) * D + d4);
    Wt[(d4 + 0) * WT_STRIDE + op] = w.x;
    Wt[(d4 + 1) * WT_STRIDE + op] = w.y;
    Wt[(d4 + 2) * WT_STRIDE + op] = w.z;
    Wt[(d4 + 3) * WT_STRIDE + op] = w.w;
  }
  // stage Xs tile: 2048 floats = 512 float4, 2 rounds
  {
    const float4* src = (const float4*)(Xs + s0 * D);
    float4* dst = (float4*)XsL;
    dst[tid]       = src[tid];
    dst[tid + 256] = src[tid + 256];
  }
  // segment counts (replicates reference valid-mask semantics)
  if (tid < SEG_PB) {
    int s   = s0 + tid;
    int rs  = graph[2 * s];
    int re  = graph[2 * s + 1];
    int nxt = (s + 1 < S) ? (graph[2 * s + 2] - 1) : (N - 1);
    re = min(re, min(nxt, N - 1));
    rs = max(rs, 0);
    cntL[tid] = (float)max(0, re - rs + 1);
  }
  __syncthreads();

  int op = tid & 63;   // local out col; whole wave shares g
  int g  = tid >> 6;   // 0..3 segment phase
  float acc[4] = {0.f, 0.f, 0.f, 0.f};

  const float4* xs4 = (const float4*)XsL;
  #pragma unroll 8
  for (int d4 = 0; d4 < D4; ++d4) {
    float w0 = Wt[(4 * d4 + 0) * WT_STRIDE + op];
    float w1 = Wt[(4 * d4 + 1) * WT_STRIDE + op];
    float w2 = Wt[(4 * d4 + 2) * WT_STRIDE + op];
    float w3 = Wt[(4 * d4 + 3) * WT_STRIDE + op];
    #pragma unroll
    for (int j = 0; j < 4; ++j) {
      float4 x = xs4[(4 * j + g) * D4 + d4];  // LDS broadcast
      acc[j] += x.x * w0 + x.y * w1 + x.z * w2 + x.w * w3;
    }
  }

  float bo = b[oBase + op];
  #pragma unroll
  for (int j = 0; j < 4; ++j) {
    int sl = 4 * j + g;
    out[(s0 + sl) * D + oBase + op] = acc[j] + cntL[sl] * bo;
  }
}

extern "C" void kernel_launch(void* const* d_in, const int* in_sizes, int n_in,
                              void* d_out, int out_size, void* d_ws, size_t ws_size,
                              hipStream_t stream) {
  const float* in    = (const float*)d_in[0];
  const int*   graph = (const int*)d_in[1];
  const float* W     = (const float*)d_in[2];
  const float* b     = (const float*)d_in[3];
  float* out = (float*)d_out;

  const int N = in_sizes[0] / D;     // 500000
  const int S = in_sizes[1] / 2;     // 10000

  float* Xs = (float*)d_ws;          // S*128 floats = 5.12 MB scratch

  // zero Xs (needed for boundary-segment atomics): S*D4 float4s / 256
  zero_kernel<<<(S * D4) / 256, 256, 0, stream>>>((float4*)Xs);

  int nChunks = (N + CHUNK - 1) / CHUNK;   // 3907
  seg_sum_kernel<<<nChunks, 256, 0, stream>>>(in, graph, Xs, N, S);

  dim3 grid2(S / SEG_PB, D / OUT_PB);  // 625 x 2
  seg_gemm_kernel<<<grid2, 256, 0, stream>>>(Xs, W, b, graph, out, N, S);
}